// Round 1
// baseline (53.371 us; speedup 1.0000x reference)
//
#include <hip/hip_runtime.h>
#include <math.h>

#define NB 8192
#define ND 512
#define NC 55
#define TCL_MARGIN 0.2f

// One block = 256 threads = 4 waves. Each block handles 32 rows.
// Thread t: class c = t&63 (clamped to 54 for lanes 55-63), rowgroup rg = t>>6.
// Each thread accumulates dot(x_row, center_c) for 8 rows (rg*8 .. rg*8+7).
// Centers staged in LDS as float4 layout [dq][56], XOR-swizzled in the low 3
// class bits by dq so both staging writes and compute reads are conflict-free.
__global__ __launch_bounds__(256, 1)
void tcl_kernel(const float* __restrict__ x, const int* __restrict__ tg,
                const float* __restrict__ cen, float* __restrict__ out,
                float* __restrict__ ws, int nblocks) {
  __shared__ float4 cenL[128 * 56];        // 114688 B
  __shared__ float xsL[32 * 64];           // 8192 B  (one 64-d chunk of 32 rows)
  __shared__ float xnormL[32];
  __shared__ float cnormL[NC];
  __shared__ unsigned long long pmL[4];
  __shared__ float blkAcc[2];

  const int t = threadIdx.x;
  const int lane = t & 63;
  const int wv = t >> 6;

  if (t == 0) { blkAcc[0] = 0.f; blkAcc[1] = 0.f; }

  // ---- class presence bitmask (targets fit in L2; 8 int4 loads/thread) ----
  unsigned long long pm = 0ull;
  {
    const int4* tg4 = (const int4*)tg;
    for (int g = t; g < NB / 4; g += 256) {
      int4 v = tg4[g];
      pm |= (1ull << v.x) | (1ull << v.y) | (1ull << v.z) | (1ull << v.w);
    }
#pragma unroll
    for (int off = 32; off; off >>= 1) pm |= __shfl_xor(pm, off);
    if (lane == 0) pmL[wv] = pm;
  }

  // ---- stage centers into LDS (coalesced global reads, swizzled LDS writes) ----
  {
    const float4* cg = (const float4*)cen;
    for (int g = t; g < NC * 128; g += 256) {
      const int c = g >> 7, dq = g & 127;
      const int cp = (c & 56) | ((c ^ dq) & 7);
      cenL[dq * 56 + cp] = cg[g];
    }
  }
  __syncthreads();
  pm = pmL[0] | pmL[1] | pmL[2] | pmL[3];

  // ---- center squared norms (220 threads, 4 per class) ----
  if (t < 4 * NC) {
    const int c = t >> 2, q = t & 3;
    float s = 0.f;
    for (int dq = q * 32; dq < q * 32 + 32; ++dq) {
      const int cp = (c & 56) | ((c ^ dq) & 7);
      const float4 v = cenL[dq * 56 + cp];
      s = fmaf(v.x, v.x, s); s = fmaf(v.y, v.y, s);
      s = fmaf(v.z, v.z, s); s = fmaf(v.w, v.w, s);
    }
    s += __shfl_xor(s, 1);
    s += __shfl_xor(s, 2);
    if (q == 0) cnormL[c] = s;
  }

  // ---- main loop: dots of 32 rows x 55 classes over D=512, chunked by 64 ----
  const int c = lane;
  const int cc = (c < NC) ? c : (NC - 1);
  const int rg = wv;
  const int blockRow0 = blockIdx.x * 32;

  float acc[8] = {0.f, 0.f, 0.f, 0.f, 0.f, 0.f, 0.f, 0.f};
  float pn0 = 0.f, pn1 = 0.f;
  const int r0 = t >> 4;   // staging row (0..15); also handles row r0+16
  const int dqx = t & 15;  // float4 slot within 64-float chunk

  const float4* xg = (const float4*)x;
  const int base0 = (blockRow0 + r0) * 128 + dqx;
  const int base1 = base0 + 16 * 128;

  float4 pre0 = xg[base0];
  float4 pre1 = xg[base1];

  for (int ch = 0; ch < 8; ++ch) {
    // write-late: deposit prefetched chunk, fold into row-norm partials
    *(float4*)&xsL[r0 * 64 + dqx * 4] = pre0;
    *(float4*)&xsL[(r0 + 16) * 64 + dqx * 4] = pre1;
    pn0 = fmaf(pre0.x, pre0.x, fmaf(pre0.y, pre0.y, fmaf(pre0.z, pre0.z, fmaf(pre0.w, pre0.w, pn0))));
    pn1 = fmaf(pre1.x, pre1.x, fmaf(pre1.y, pre1.y, fmaf(pre1.z, pre1.z, fmaf(pre1.w, pre1.w, pn1))));
    __syncthreads();
    // issue-early: next chunk's global loads hide under the FMA block below
    if (ch < 7) {
      pre0 = xg[base0 + (ch + 1) * 16];
      pre1 = xg[base1 + (ch + 1) * 16];
    }
#pragma unroll
    for (int dq = 0; dq < 16; ++dq) {
      const int dqg = ch * 16 + dq;
      const int cp = (cc & 56) | ((cc ^ dqg) & 7);
      const float4 cv = cenL[dqg * 56 + cp];
#pragma unroll
      for (int j = 0; j < 8; ++j) {
        const float4 xv = *(const float4*)&xsL[(rg * 8 + j) * 64 + dq * 4];
        acc[j] = fmaf(cv.x, xv.x, acc[j]);
        acc[j] = fmaf(cv.y, xv.y, acc[j]);
        acc[j] = fmaf(cv.z, xv.z, acc[j]);
        acc[j] = fmaf(cv.w, xv.w, acc[j]);
      }
    }
    __syncthreads();
  }

  // ---- x row norms: reduce 16 staging lanes per row ----
  {
    float s0 = pn0, s1 = pn1;
#pragma unroll
    for (int off = 8; off; off >>= 1) {
      s0 += __shfl_xor(s0, off);
      s1 += __shfl_xor(s1, off);
    }
    if (dqx == 0) { xnormL[r0] = s0; xnormL[r0 + 16] = s1; }
  }
  __syncthreads();

  // ---- epilogue: dist, ap/an, loss & prec partials ----
  const float cn = cnormL[cc];
  float wl = 0.f, wp = 0.f;
#pragma unroll
  for (int j = 0; j < 8; ++j) {
    const int lrow = rg * 8 + j;
    const int grow = blockRow0 + lrow;
    const int tj = tg[grow];
    float sq = xnormL[lrow] + cn - 2.0f * acc[j];
    sq = fmaxf(sq, 1e-12f);
    const float dist = sqrtf(sq);
    const float ap = __shfl(dist, tj);  // lane tj holds D[row, tj]
    const bool valid = (c < NC) && (c != tj) && (((pm >> c) & 1ull) != 0ull);
    float anv = valid ? dist : INFINITY;
#pragma unroll
    for (int off = 32; off; off >>= 1) anv = fminf(anv, __shfl_xor(anv, off));
    if (lane == 0) {
      wl += fmaxf(ap - anv + TCL_MARGIN, 0.f);
      wp += (anv > ap) ? 1.f : 0.f;
    }
  }
  if (lane == 0) {
    atomicAdd(&blkAcc[0], wl);
    atomicAdd(&blkAcc[1], wp);
  }
  __syncthreads();
  if (t == 0) {
    atomicAdd(&ws[0], blkAcc[0]);
    atomicAdd(&ws[1], blkAcc[1]);
    __threadfence();
    const unsigned int prev = atomicAdd((unsigned int*)(ws + 2), 1u);
    if (prev == (unsigned int)(nblocks - 1)) {
      __threadfence();
      const float L = atomicAdd(&ws[0], 0.f);
      const float P = atomicAdd(&ws[1], 0.f);
      out[0] = L * (1.0f / NB);
      out[1] = P * (1.0f / NB);
    }
  }
}

extern "C" void kernel_launch(void* const* d_in, const int* in_sizes, int n_in,
                              void* d_out, int out_size, void* d_ws, size_t ws_size,
                              hipStream_t stream) {
  const float* x = (const float*)d_in[0];    // [8192, 512] f32
  const int* tg = (const int*)d_in[1];       // [8192] int32
  const float* cen = (const float*)d_in[2];  // [55, 512] f32
  float* out = (float*)d_out;                // [loss, prec]
  float* ws = (float*)d_ws;

  hipMemsetAsync(d_ws, 0, 64, stream);  // loss-sum, prec-sum, done-counter
  tcl_kernel<<<dim3(NB / 32), dim3(256), 0, stream>>>(x, tg, cen, out, ws, NB / 32);
}

// Round 2
// 52.457 us; speedup vs baseline: 1.0174x; 1.0174x over previous
//
#include <hip/hip_runtime.h>
#include <math.h>

#define NB 8192
#define ND 512
#define NC 55
#define NCP 64
#define TCL_MARGIN 0.2f

typedef __attribute__((ext_vector_type(8))) short short8;
typedef __attribute__((ext_vector_type(4))) short shortx4;
typedef __attribute__((ext_vector_type(4))) float f32x4;

// round-to-nearest-even fp32 -> bf16 (bit trick, sign-safe)
__device__ __forceinline__ unsigned short bf16rne(float v) {
  unsigned int u = __float_as_uint(v);
  unsigned int r = u + 0x7FFFu + ((u >> 16) & 1u);
  return (unsigned short)(r >> 16);
}

// ws layout (bytes):
//   0: lossSum f32 | 4: precSum f32 | 8: done u32 | 16..272: cnorm[64] f32
//   512:    cenh bf16[64][512]   (65536 B)
//   66048:  cenl bf16[64][512]   (65536 B)
__global__ __launch_bounds__(64)
void tcl_prep(const float* __restrict__ cen, float* __restrict__ ws) {
  const int c = blockIdx.x;   // padded class 0..63
  const int t = threadIdx.x;  // 0..63
  unsigned short* ch = (unsigned short*)((char*)ws + 512) + c * ND;
  unsigned short* cl = (unsigned short*)((char*)ws + 66048) + c * ND;
  float s = 0.f;
#pragma unroll
  for (int i = 0; i < 2; ++i) {
    const int q = t + 64 * i;  // float4 index within the row
    float4 v = make_float4(0.f, 0.f, 0.f, 0.f);
    if (c < NC) v = ((const float4*)(cen + c * ND))[q];
    shortx4 h, lo;
    unsigned short hu;
    hu = bf16rne(v.x); h.x = (short)hu; lo.x = (short)bf16rne(v.x - __uint_as_float((unsigned)hu << 16));
    hu = bf16rne(v.y); h.y = (short)hu; lo.y = (short)bf16rne(v.y - __uint_as_float((unsigned)hu << 16));
    hu = bf16rne(v.z); h.z = (short)hu; lo.z = (short)bf16rne(v.z - __uint_as_float((unsigned)hu << 16));
    hu = bf16rne(v.w); h.w = (short)hu; lo.w = (short)bf16rne(v.w - __uint_as_float((unsigned)hu << 16));
    s = fmaf(v.x, v.x, s); s = fmaf(v.y, v.y, s);
    s = fmaf(v.z, v.z, s); s = fmaf(v.w, v.w, s);
    *(shortx4*)(ch + q * 4) = h;
    *(shortx4*)(cl + q * 4) = lo;
  }
#pragma unroll
  for (int off = 32; off; off >>= 1) s += __shfl_xor(s, off);
  if (t == 0) ws[4 + c] = s;  // cnorm[c]
}

// Main: 256 blocks x 128 threads (2 waves). Block handles 32 rows x all 64 cols.
// Wave w computes rows w*16..w*16+15 via mfma_f32_16x16x32_bf16, 4 col-tiles,
// 16 K-steps, 3 split-MFMAs each. A from swizzled LDS, B from L2-resident ws.
__global__ __launch_bounds__(128)
void tcl_main(const float* __restrict__ x, const int* __restrict__ tg,
              float* __restrict__ ws, float* __restrict__ out, int nblocks) {
  __shared__ alignas(16) char xs[2][32 * 1024];  // bf16 hi/lo, 32 rows x 512, XOR-swizzled
  __shared__ float distL[32][64];
  __shared__ float cnL[64];
  __shared__ float xnormL[32];
  __shared__ float xnp[2][32];
  __shared__ unsigned long long pmL[2];
  __shared__ float blkAcc[2];

  const int t = threadIdx.x;
  const int l = t & 63;
  const int w = t >> 6;
  const int row0 = blockIdx.x * 32;

  if (t == 0) { blkAcc[0] = 0.f; blkAcc[1] = 0.f; }
  if (t < 64) cnL[t] = ws[4 + t];

  // ---- stage + convert X tile (fp32 -> bf16 hi/lo, swizzled) + row-norm partials ----
  const float4* xg = (const float4*)(x + row0 * ND);
  for (int i = 0; i < 32; ++i) {  // i = row
    float4 v = xg[i * 128 + t];
    shortx4 h, lo;
    unsigned short hu;
    hu = bf16rne(v.x); h.x = (short)hu; lo.x = (short)bf16rne(v.x - __uint_as_float((unsigned)hu << 16));
    hu = bf16rne(v.y); h.y = (short)hu; lo.y = (short)bf16rne(v.y - __uint_as_float((unsigned)hu << 16));
    hu = bf16rne(v.z); h.z = (short)hu; lo.z = (short)bf16rne(v.z - __uint_as_float((unsigned)hu << 16));
    hu = bf16rne(v.w); h.w = (short)hu; lo.w = (short)bf16rne(v.w - __uint_as_float((unsigned)hu << 16));
    const int kb = (t * 8) ^ ((i & 7) << 4);  // byte offset in row, XOR-swizzled
    *(shortx4*)&xs[0][i * 1024 + kb] = h;
    *(shortx4*)&xs[1][i * 1024 + kb] = lo;
    float p = v.x * v.x + v.y * v.y + v.z * v.z + v.w * v.w;
#pragma unroll
    for (int off = 32; off; off >>= 1) p += __shfl_xor(p, off);
    if (l == 0) xnp[w][i] = p;
  }

  // ---- class presence bitmask ----
  unsigned long long pm = 0ull;
  {
    const int4* tg4 = (const int4*)tg;
    for (int g = t; g < NB / 4; g += 128) {
      int4 tv = tg4[g];
      pm |= (1ull << tv.x) | (1ull << tv.y) | (1ull << tv.z) | (1ull << tv.w);
    }
#pragma unroll
    for (int off = 32; off; off >>= 1) pm |= __shfl_xor(pm, off);
    if (l == 0) pmL[w] = pm;
  }

  __syncthreads();
  pm = pmL[0] | pmL[1];
  if (t < 32) xnormL[t] = xnp[0][t] + xnp[1][t];

  // ---- MFMA: S[16x64] per wave, K=512, split-bf16 (hh + lh + hl) ----
  f32x4 acc[4] = {{0.f,0.f,0.f,0.f},{0.f,0.f,0.f,0.f},{0.f,0.f,0.f,0.f},{0.f,0.f,0.f,0.f}};
  {
    const int rowA = w * 16 + (l & 15);
    const int sw = (rowA & 7) << 4;
    const int kg = (l >> 4) * 16;  // byte offset of this lane's k-group
    const char* xh = &xs[0][rowA * 1024];
    const char* xl = &xs[1][rowA * 1024];
    const char* bhb = (const char*)ws + 512 + (l & 15) * 1024 + kg;
    const char* blb = (const char*)ws + 66048 + (l & 15) * 1024 + kg;
#pragma unroll 4
    for (int ks = 0; ks < 16; ++ks) {
      const int ka = (ks * 64 + kg) ^ sw;
      short8 ah = *(const short8*)(xh + ka);
      short8 al = *(const short8*)(xl + ka);
#pragma unroll
      for (int ct = 0; ct < 4; ++ct) {
        short8 bh = *(const short8*)(bhb + ct * 16384 + ks * 64);
        short8 bl = *(const short8*)(blb + ct * 16384 + ks * 64);
        acc[ct] = __builtin_amdgcn_mfma_f32_16x16x32_bf16(ah, bh, acc[ct], 0, 0, 0);
        acc[ct] = __builtin_amdgcn_mfma_f32_16x16x32_bf16(al, bh, acc[ct], 0, 0, 0);
        acc[ct] = __builtin_amdgcn_mfma_f32_16x16x32_bf16(ah, bl, acc[ct], 0, 0, 0);
      }
    }
  }
  __syncthreads();  // xnormL ready; xs no longer needed

  // ---- dist tile: C/D layout col=lane&15, row=(lane>>4)*4+reg ----
  {
    const int rr = (l >> 4) * 4;
#pragma unroll
    for (int ct = 0; ct < 4; ++ct) {
      const int col = ct * 16 + (l & 15);
      const float cn = cnL[col];
#pragma unroll
      for (int r = 0; r < 4; ++r) {
        const int row = w * 16 + rr + r;
        float sq = xnormL[row] + cn - 2.0f * acc[ct][r];
        sq = fmaxf(sq, 1e-12f);
        distL[row][col] = sqrtf(sq);
      }
    }
  }
  __syncthreads();

  // ---- epilogue: ap/an per row, loss & prec partials ----
  float wl = 0.f, wp = 0.f;
#pragma unroll
  for (int j = 0; j < 16; ++j) {
    const int row = w * 16 + j;
    const int tj = tg[row0 + row];
    const float d = distL[row][l];
    const float ap = __shfl(d, tj);  // lane tj holds D[row, tj]
    const bool valid = (l < NC) && (l != tj) && (((pm >> l) & 1ull) != 0ull);
    float anv = valid ? d : INFINITY;
#pragma unroll
    for (int off = 32; off; off >>= 1) anv = fminf(anv, __shfl_xor(anv, off));
    if (l == 0) {
      wl += fmaxf(ap - anv + TCL_MARGIN, 0.f);
      wp += (anv > ap) ? 1.f : 0.f;
    }
  }
  if (l == 0) { atomicAdd(&blkAcc[0], wl); atomicAdd(&blkAcc[1], wp); }
  __syncthreads();
  if (t == 0) {
    atomicAdd(&ws[0], blkAcc[0]);
    atomicAdd(&ws[1], blkAcc[1]);
    __threadfence();
    const unsigned int prev = atomicAdd((unsigned int*)ws + 2, 1u);
    if (prev == (unsigned int)(nblocks - 1)) {
      __threadfence();
      out[0] = atomicAdd(&ws[0], 0.f) * (1.0f / NB);
      out[1] = atomicAdd(&ws[1], 0.f) * (1.0f / NB);
    }
  }
}

extern "C" void kernel_launch(void* const* d_in, const int* in_sizes, int n_in,
                              void* d_out, int out_size, void* d_ws, size_t ws_size,
                              hipStream_t stream) {
  const float* x = (const float*)d_in[0];    // [8192, 512] f32
  const int* tg = (const int*)d_in[1];       // [8192] int32
  const float* cen = (const float*)d_in[2];  // [55, 512] f32
  float* out = (float*)d_out;                // [loss, prec]
  float* ws = (float*)d_ws;

  hipMemsetAsync(d_ws, 0, 16, stream);                      // loss, prec, done
  tcl_prep<<<dim3(NCP), dim3(64), 0, stream>>>(cen, ws);    // centers -> bf16 hi/lo + cnorm
  tcl_main<<<dim3(NB / 32), dim3(128), 0, stream>>>(x, tg, ws, out, NB / 32);
}

// Round 4
// 45.062 us; speedup vs baseline: 1.1844x; 1.1641x over previous
//
#include <hip/hip_runtime.h>
#include <math.h>

#define NB 8192
#define ND 512
#define NC 55
#define TCL_MARGIN 0.2f

typedef __attribute__((ext_vector_type(8))) short short8;
typedef __attribute__((ext_vector_type(4))) short shortx4;
typedef __attribute__((ext_vector_type(4))) float f32x4;

// round-to-nearest-even fp32 -> bf16 (bit trick, sign-safe)
__device__ __forceinline__ unsigned short bf16rne(float v) {
  unsigned int u = __float_as_uint(v);
  unsigned int r = u + 0x7FFFu + ((u >> 16) & 1u);
  return (unsigned short)(r >> 16);
}

// split one f32 into bf16 hi (bits 31:16 of result) + bf16 lo residual (15:0)
__device__ __forceinline__ unsigned int bfsplit2(float v) {
  unsigned short hu = bf16rne(v);
  unsigned short lu = bf16rne(v - __uint_as_float((unsigned)hu << 16));
  return ((unsigned int)hu << 16) | (unsigned int)lu;
}

// ws layout (bytes):
//   0: lossSum f32 | 4: precSum f32 | 8: done u32 | 16: presence u64
//   32..288:  cnorm[64] f32                (float idx 8..71)
//   512:      cenh bf16[64][512] (65536 B)
//   66048:    cenl bf16[64][512] (65536 B)
__global__ __launch_bounds__(64)
void tcl_prep(const float* __restrict__ cen, const int* __restrict__ tg,
              float* __restrict__ ws) {
  const int c = blockIdx.x;   // 0..63 centers, 64 = presence bitmask
  const int t = threadIdx.x;  // 0..63

  if (c == 64) {
    // presence bitmask over all 8192 targets: 2048 int4, 4 accumulators for MLP
    const int4* tg4 = (const int4*)tg;
    unsigned long long p0 = 0, p1 = 0, p2 = 0, p3 = 0;
    for (int g = 0; g < NB / 4; g += 256) {
      int4 a = tg4[g + t];
      int4 b = tg4[g + 64 + t];
      int4 e = tg4[g + 128 + t];
      int4 d = tg4[g + 192 + t];
      p0 |= (1ull << a.x) | (1ull << a.y) | (1ull << a.z) | (1ull << a.w);
      p1 |= (1ull << b.x) | (1ull << b.y) | (1ull << b.z) | (1ull << b.w);
      p2 |= (1ull << e.x) | (1ull << e.y) | (1ull << e.z) | (1ull << e.w);
      p3 |= (1ull << d.x) | (1ull << d.y) | (1ull << d.z) | (1ull << d.w);
    }
    unsigned long long pm = (p0 | p1) | (p2 | p3);
#pragma unroll
    for (int off = 32; off; off >>= 1) pm |= __shfl_xor(pm, off);
    if (t == 0) *(unsigned long long*)((char*)ws + 16) = pm;
    return;
  }

  // convert center row c -> bf16 hi/lo, compute cnorm
  unsigned short* ch = (unsigned short*)((char*)ws + 512) + c * ND;
  unsigned short* cl = (unsigned short*)((char*)ws + 66048) + c * ND;
  float s = 0.f;
#pragma unroll
  for (int i = 0; i < 2; ++i) {
    const int q = t + 64 * i;  // float4 index within the row
    float4 v = make_float4(0.f, 0.f, 0.f, 0.f);
    if (c < NC) v = ((const float4*)(cen + c * ND))[q];
    shortx4 h, lo;
    unsigned int p;
    p = bfsplit2(v.x); h.x = (short)(p >> 16); lo.x = (short)(p & 0xFFFF);
    p = bfsplit2(v.y); h.y = (short)(p >> 16); lo.y = (short)(p & 0xFFFF);
    p = bfsplit2(v.z); h.z = (short)(p >> 16); lo.z = (short)(p & 0xFFFF);
    p = bfsplit2(v.w); h.w = (short)(p >> 16); lo.w = (short)(p & 0xFFFF);
    s = fmaf(v.x, v.x, s); s = fmaf(v.y, v.y, s);
    s = fmaf(v.z, v.z, s); s = fmaf(v.w, v.w, s);
    *(shortx4*)(ch + q * 4) = h;
    *(shortx4*)(cl + q * 4) = lo;
  }
#pragma unroll
  for (int off = 32; off; off >>= 1) s += __shfl_xor(s, off);
  if (t == 0) ws[8 + c] = s;  // cnorm[c]
}

// Main: 512 blocks x 256 threads (4 waves). Block = 16 rows x 64 cols, K=512.
// Split-K: wave w handles K in [w*128, w*128+128) = 4 k-steps of 32.
// A fragments loaded per-lane directly from x (f32) and converted in regs.
// B fragments from L2-resident converted centers in ws.
// Wave 0 reduces partials from LDS and runs an all-register epilogue.
__global__ __launch_bounds__(256)
void tcl_main(const float* __restrict__ x, const int* __restrict__ tg,
              float* __restrict__ ws, float* __restrict__ out, int nblocks) {
  __shared__ f32x4 accL[3][4][64];  // waves 1..3 partial accs, 12 KB
  __shared__ float xnL[4][16];      // per-wave partial row norms

  const int t = threadIdx.x;
  const int l = t & 63;
  const int w = t >> 6;
  const int row0 = blockIdx.x * 16;
  const int rlo = l & 15;        // A row within tile / B col within ct
  const int kgE = (l >> 4) * 8;  // element offset of this lane's k-group

  // ---- issue all 8 A loads (independent, in flight together) ----
  const float* xr = x + (row0 + rlo) * ND;
  float4 va[4][2];
#pragma unroll
  for (int ksl = 0; ksl < 4; ++ksl) {
    const int k0 = (w * 4 + ksl) * 32 + kgE;
    va[ksl][0] = *(const float4*)(xr + k0);
    va[ksl][1] = *(const float4*)(xr + k0 + 4);
  }

  // ---- row-norm partial over this wave's K range ----
  float xn = 0.f;
#pragma unroll
  for (int ksl = 0; ksl < 4; ++ksl) {
    float4 a = va[ksl][0], b = va[ksl][1];
    xn = fmaf(a.x, a.x, xn); xn = fmaf(a.y, a.y, xn);
    xn = fmaf(a.z, a.z, xn); xn = fmaf(a.w, a.w, xn);
    xn = fmaf(b.x, b.x, xn); xn = fmaf(b.y, b.y, xn);
    xn = fmaf(b.z, b.z, xn); xn = fmaf(b.w, b.w, xn);
  }
  xn += __shfl_xor(xn, 16);
  xn += __shfl_xor(xn, 32);
  if (l < 16) xnL[w][l] = xn;

  // ---- convert + MFMA: 4 k-steps x 4 col-tiles x 3 split-MFMAs ----
  f32x4 acc[4] = {{0.f,0.f,0.f,0.f},{0.f,0.f,0.f,0.f},{0.f,0.f,0.f,0.f},{0.f,0.f,0.f,0.f}};
  {
    const char* bh0 = (const char*)ws + 512 + rlo * 1024 + (l >> 4) * 16;
    const char* bl0 = (const char*)ws + 66048 + rlo * 1024 + (l >> 4) * 16;
#pragma unroll
    for (int ksl = 0; ksl < 4; ++ksl) {
      short8 ah, al;
      {
        float4 a = va[ksl][0], b = va[ksl][1];
        unsigned int p;
        p = bfsplit2(a.x); ah[0] = (short)(p >> 16); al[0] = (short)(p & 0xFFFF);
        p = bfsplit2(a.y); ah[1] = (short)(p >> 16); al[1] = (short)(p & 0xFFFF);
        p = bfsplit2(a.z); ah[2] = (short)(p >> 16); al[2] = (short)(p & 0xFFFF);
        p = bfsplit2(a.w); ah[3] = (short)(p >> 16); al[3] = (short)(p & 0xFFFF);
        p = bfsplit2(b.x); ah[4] = (short)(p >> 16); al[4] = (short)(p & 0xFFFF);
        p = bfsplit2(b.y); ah[5] = (short)(p >> 16); al[5] = (short)(p & 0xFFFF);
        p = bfsplit2(b.z); ah[6] = (short)(p >> 16); al[6] = (short)(p & 0xFFFF);
        p = bfsplit2(b.w); ah[7] = (short)(p >> 16); al[7] = (short)(p & 0xFFFF);
      }
      const int kb = (w * 4 + ksl) * 64;  // byte offset per k-chunk (32 elts * 2 B)
#pragma unroll
      for (int ct = 0; ct < 4; ++ct) {
        short8 bh = *(const short8*)(bh0 + ct * 16384 + kb);
        short8 bl = *(const short8*)(bl0 + ct * 16384 + kb);
        acc[ct] = __builtin_amdgcn_mfma_f32_16x16x32_bf16(ah, bh, acc[ct], 0, 0, 0);
        acc[ct] = __builtin_amdgcn_mfma_f32_16x16x32_bf16(al, bh, acc[ct], 0, 0, 0);
        acc[ct] = __builtin_amdgcn_mfma_f32_16x16x32_bf16(ah, bl, acc[ct], 0, 0, 0);
      }
    }
  }

  if (w) {
#pragma unroll
    for (int ct = 0; ct < 4; ++ct) accL[w - 1][ct][l] = acc[ct];
  }
  __syncthreads();
  if (w != 0) return;

  // ---- wave 0: reduce partials ----
#pragma unroll
  for (int wv = 0; wv < 3; ++wv)
#pragma unroll
    for (int ct = 0; ct < 4; ++ct) {
      f32x4 p = accL[wv][ct][l];
      acc[ct][0] += p[0]; acc[ct][1] += p[1];
      acc[ct][2] += p[2]; acc[ct][3] += p[3];
    }
  float xns = (l < 16) ? (xnL[0][l] + xnL[1][l] + xnL[2][l] + xnL[3][l]) : 0.f;

  // ---- epilogue, all in registers ----
  const float cnl = ws[8 + l];                     // cnorm[col l]
  const int tgl = (l < 16) ? tg[row0 + l] : 0;     // target of row l
  const unsigned long long pmv = *(const unsigned long long*)((const char*)ws + 16);
  float cn[4];
#pragma unroll
  for (int ct = 0; ct < 4; ++ct) cn[ct] = __shfl(cnl, ct * 16 + rlo);
  // col validity independent of row: col < NC && present
  bool cv[4];
#pragma unroll
  for (int ct = 0; ct < 4; ++ct) {
    const int col = ct * 16 + rlo;
    cv[ct] = (col < NC) && (((pmv >> col) & 1ull) != 0ull);
  }

  const int g4 = (l >> 4) * 4;  // first row of this lane's row-group
  float wl = 0.f, wp = 0.f;
#pragma unroll
  for (int r = 0; r < 4; ++r) {
    const int row = g4 + r;
    const int tjr = __shfl(tgl, row);
    const float xnr = __shfl(xns, row);
    const float s0 = fmaxf(xnr + cn[0] - 2.0f * acc[0][r], 1e-12f);
    const float s1 = fmaxf(xnr + cn[1] - 2.0f * acc[1][r], 1e-12f);
    const float s2 = fmaxf(xnr + cn[2] - 2.0f * acc[2][r], 1e-12f);
    const float s3 = fmaxf(xnr + cn[3] - 2.0f * acc[3][r], 1e-12f);
    // hardest positive: D[row, tjr]
    const int c2 = tjr >> 4;
    const float dsel = (c2 == 0) ? s0 : (c2 == 1) ? s1 : (c2 == 2) ? s2 : s3;
    const float apq = __shfl(dsel, (l & 48) | (tjr & 15));
    // hardest negative: min over valid cols != tjr
    const float INF = __builtin_inff();
    float m0 = (cv[0] && (rlo != tjr)) ? s0 : INF;
    float m1 = (cv[1] && (16 + rlo != tjr)) ? s1 : INF;
    float m2 = (cv[2] && (32 + rlo != tjr)) ? s2 : INF;
    float m3 = (cv[3] && (48 + rlo != tjr)) ? s3 : INF;
    float mn = fminf(fminf(m0, m1), fminf(m2, m3));
    mn = fminf(mn, __shfl_xor(mn, 1));
    mn = fminf(mn, __shfl_xor(mn, 2));
    mn = fminf(mn, __shfl_xor(mn, 4));
    mn = fminf(mn, __shfl_xor(mn, 8));
    if (rlo == 0) {
      const float ap = sqrtf(apq), an = sqrtf(mn);
      wl += fmaxf(ap - an + TCL_MARGIN, 0.f);
      wp += (an > ap) ? 1.f : 0.f;
    }
  }
  wl += __shfl_xor(wl, 16); wl += __shfl_xor(wl, 32);
  wp += __shfl_xor(wp, 16); wp += __shfl_xor(wp, 32);

  if (l == 0) {
    atomicAdd(&ws[0], wl);
    atomicAdd(&ws[1], wp);
    __threadfence();
    const unsigned int prev = atomicAdd((unsigned int*)ws + 2, 1u);
    if (prev == (unsigned int)(nblocks - 1)) {
      __threadfence();
      out[0] = atomicAdd(&ws[0], 0.f) * (1.0f / NB);
      out[1] = atomicAdd(&ws[1], 0.f) * (1.0f / NB);
    }
  }
}

extern "C" void kernel_launch(void* const* d_in, const int* in_sizes, int n_in,
                              void* d_out, int out_size, void* d_ws, size_t ws_size,
                              hipStream_t stream) {
  const float* x = (const float*)d_in[0];    // [8192, 512] f32
  const int* tg = (const int*)d_in[1];       // [8192] int32
  const float* cen = (const float*)d_in[2];  // [55, 512] f32
  float* out = (float*)d_out;                // [loss, prec]
  float* ws = (float*)d_ws;

  (void)hipMemsetAsync(d_ws, 0, 32, stream);  // loss, prec, done, pm
  tcl_prep<<<dim3(65), dim3(64), 0, stream>>>(cen, tg, ws);
  tcl_main<<<dim3(NB / 16), dim3(256), 0, stream>>>(x, tg, ws, out, NB / 16);
}

// Round 5
// 41.804 us; speedup vs baseline: 1.2767x; 1.0780x over previous
//
#include <hip/hip_runtime.h>
#include <math.h>

#define NB 8192
#define ND 512
#define NC 55
#define TCL_MARGIN 0.2f

typedef __attribute__((ext_vector_type(8))) short short8;
typedef __attribute__((ext_vector_type(4))) short shortx4;
typedef __attribute__((ext_vector_type(4))) float f32x4;

// round-to-nearest-even fp32 -> bf16 (bit trick, sign-safe)
__device__ __forceinline__ unsigned short bf16rne(float v) {
  unsigned int u = __float_as_uint(v);
  unsigned int r = u + 0x7FFFu + ((u >> 16) & 1u);
  return (unsigned short)(r >> 16);
}

// split one f32 into bf16 hi (bits 31:16 of result) + bf16 lo residual (15:0)
__device__ __forceinline__ unsigned int bfsplit2(float v) {
  unsigned short hu = bf16rne(v);
  unsigned short lu = bf16rne(v - __uint_as_float((unsigned)hu << 16));
  return ((unsigned int)hu << 16) | (unsigned int)lu;
}

// ws layout (bytes):
//   0: lossSum f32 | 4: precSum f32 | 8: done u32 | 16: presence u64
//   32..288:  cnorm[64] f32                (float idx 8..71)
//   512:      cenh bf16[64][512] (65536 B)
//   66048:    cenl bf16[64][512] (65536 B)
__global__ __launch_bounds__(64)
void tcl_prep(const float* __restrict__ cen, const int* __restrict__ tg,
              float* __restrict__ ws) {
  const int c = blockIdx.x;   // 0..63 centers, 64 = presence bitmask + accumulator reset
  const int t = threadIdx.x;  // 0..63

  if (c == 64) {
    // zero the cross-call accumulators (replaces the 40us hipMemsetAsync dispatch;
    // stream order guarantees this lands before tcl_main's atomics)
    if (t == 0) {
      ws[0] = 0.f;                       // loss sum
      ws[1] = 0.f;                       // prec sum
      ((unsigned int*)ws)[2] = 0u;       // done counter
    }
    // presence bitmask over all 8192 targets: 2048 int4, 4 accumulators for MLP
    const int4* tg4 = (const int4*)tg;
    unsigned long long p0 = 0, p1 = 0, p2 = 0, p3 = 0;
    for (int g = 0; g < NB / 4; g += 256) {
      int4 a = tg4[g + t];
      int4 b = tg4[g + 64 + t];
      int4 e = tg4[g + 128 + t];
      int4 d = tg4[g + 192 + t];
      p0 |= (1ull << a.x) | (1ull << a.y) | (1ull << a.z) | (1ull << a.w);
      p1 |= (1ull << b.x) | (1ull << b.y) | (1ull << b.z) | (1ull << b.w);
      p2 |= (1ull << e.x) | (1ull << e.y) | (1ull << e.z) | (1ull << e.w);
      p3 |= (1ull << d.x) | (1ull << d.y) | (1ull << d.z) | (1ull << d.w);
    }
    unsigned long long pm = (p0 | p1) | (p2 | p3);
#pragma unroll
    for (int off = 32; off; off >>= 1) pm |= __shfl_xor(pm, off);
    if (t == 0) *(unsigned long long*)((char*)ws + 16) = pm;
    return;
  }

  // convert center row c -> bf16 hi/lo, compute cnorm
  unsigned short* ch = (unsigned short*)((char*)ws + 512) + c * ND;
  unsigned short* cl = (unsigned short*)((char*)ws + 66048) + c * ND;
  float s = 0.f;
#pragma unroll
  for (int i = 0; i < 2; ++i) {
    const int q = t + 64 * i;  // float4 index within the row
    float4 v = make_float4(0.f, 0.f, 0.f, 0.f);
    if (c < NC) v = ((const float4*)(cen + c * ND))[q];
    shortx4 h, lo;
    unsigned int p;
    p = bfsplit2(v.x); h.x = (short)(p >> 16); lo.x = (short)(p & 0xFFFF);
    p = bfsplit2(v.y); h.y = (short)(p >> 16); lo.y = (short)(p & 0xFFFF);
    p = bfsplit2(v.z); h.z = (short)(p >> 16); lo.z = (short)(p & 0xFFFF);
    p = bfsplit2(v.w); h.w = (short)(p >> 16); lo.w = (short)(p & 0xFFFF);
    s = fmaf(v.x, v.x, s); s = fmaf(v.y, v.y, s);
    s = fmaf(v.z, v.z, s); s = fmaf(v.w, v.w, s);
    *(shortx4*)(ch + q * 4) = h;
    *(shortx4*)(cl + q * 4) = lo;
  }
#pragma unroll
  for (int off = 32; off; off >>= 1) s += __shfl_xor(s, off);
  if (t == 0) ws[8 + c] = s;  // cnorm[c]
}

// Main: 512 blocks x 256 threads (4 waves). Block = 16 rows x 64 cols, K=512.
// Split-K: wave w handles K in [w*128, w*128+128) = 4 k-steps of 32.
// A fragments loaded per-lane directly from x (f32) and converted in regs.
// B fragments from L2-resident converted centers in ws.
// Wave 0 reduces partials from LDS and runs an all-register epilogue.
__global__ __launch_bounds__(256)
void tcl_main(const float* __restrict__ x, const int* __restrict__ tg,
              float* __restrict__ ws, float* __restrict__ out, int nblocks) {
  __shared__ f32x4 accL[3][4][64];  // waves 1..3 partial accs, 12 KB
  __shared__ float xnL[4][16];      // per-wave partial row norms

  const int t = threadIdx.x;
  const int l = t & 63;
  const int w = t >> 6;
  const int row0 = blockIdx.x * 16;
  const int rlo = l & 15;        // A row within tile / B col within ct
  const int kgE = (l >> 4) * 8;  // element offset of this lane's k-group

  // ---- issue all 8 A loads (independent, in flight together) ----
  const float* xr = x + (row0 + rlo) * ND;
  float4 va[4][2];
#pragma unroll
  for (int ksl = 0; ksl < 4; ++ksl) {
    const int k0 = (w * 4 + ksl) * 32 + kgE;
    va[ksl][0] = *(const float4*)(xr + k0);
    va[ksl][1] = *(const float4*)(xr + k0 + 4);
  }

  // ---- row-norm partial over this wave's K range ----
  float xn = 0.f;
#pragma unroll
  for (int ksl = 0; ksl < 4; ++ksl) {
    float4 a = va[ksl][0], b = va[ksl][1];
    xn = fmaf(a.x, a.x, xn); xn = fmaf(a.y, a.y, xn);
    xn = fmaf(a.z, a.z, xn); xn = fmaf(a.w, a.w, xn);
    xn = fmaf(b.x, b.x, xn); xn = fmaf(b.y, b.y, xn);
    xn = fmaf(b.z, b.z, xn); xn = fmaf(b.w, b.w, xn);
  }
  xn += __shfl_xor(xn, 16);
  xn += __shfl_xor(xn, 32);
  if (l < 16) xnL[w][l] = xn;

  // ---- convert + MFMA: 4 k-steps x 4 col-tiles x 3 split-MFMAs ----
  f32x4 acc[4] = {{0.f,0.f,0.f,0.f},{0.f,0.f,0.f,0.f},{0.f,0.f,0.f,0.f},{0.f,0.f,0.f,0.f}};
  {
    const char* bh0 = (const char*)ws + 512 + rlo * 1024 + (l >> 4) * 16;
    const char* bl0 = (const char*)ws + 66048 + rlo * 1024 + (l >> 4) * 16;
#pragma unroll
    for (int ksl = 0; ksl < 4; ++ksl) {
      short8 ah, al;
      {
        float4 a = va[ksl][0], b = va[ksl][1];
        unsigned int p;
        p = bfsplit2(a.x); ah[0] = (short)(p >> 16); al[0] = (short)(p & 0xFFFF);
        p = bfsplit2(a.y); ah[1] = (short)(p >> 16); al[1] = (short)(p & 0xFFFF);
        p = bfsplit2(a.z); ah[2] = (short)(p >> 16); al[2] = (short)(p & 0xFFFF);
        p = bfsplit2(a.w); ah[3] = (short)(p >> 16); al[3] = (short)(p & 0xFFFF);
        p = bfsplit2(b.x); ah[4] = (short)(p >> 16); al[4] = (short)(p & 0xFFFF);
        p = bfsplit2(b.y); ah[5] = (short)(p >> 16); al[5] = (short)(p & 0xFFFF);
        p = bfsplit2(b.z); ah[6] = (short)(p >> 16); al[6] = (short)(p & 0xFFFF);
        p = bfsplit2(b.w); ah[7] = (short)(p >> 16); al[7] = (short)(p & 0xFFFF);
      }
      const int kb = (w * 4 + ksl) * 64;  // byte offset per k-chunk (32 elts * 2 B)
#pragma unroll
      for (int ct = 0; ct < 4; ++ct) {
        short8 bh = *(const short8*)(bh0 + ct * 16384 + kb);
        short8 bl = *(const short8*)(bl0 + ct * 16384 + kb);
        acc[ct] = __builtin_amdgcn_mfma_f32_16x16x32_bf16(ah, bh, acc[ct], 0, 0, 0);
        acc[ct] = __builtin_amdgcn_mfma_f32_16x16x32_bf16(al, bh, acc[ct], 0, 0, 0);
        acc[ct] = __builtin_amdgcn_mfma_f32_16x16x32_bf16(ah, bl, acc[ct], 0, 0, 0);
      }
    }
  }

  if (w) {
#pragma unroll
    for (int ct = 0; ct < 4; ++ct) accL[w - 1][ct][l] = acc[ct];
  }
  __syncthreads();
  if (w != 0) return;

  // ---- wave 0: reduce partials ----
#pragma unroll
  for (int wv = 0; wv < 3; ++wv)
#pragma unroll
    for (int ct = 0; ct < 4; ++ct) {
      f32x4 p = accL[wv][ct][l];
      acc[ct][0] += p[0]; acc[ct][1] += p[1];
      acc[ct][2] += p[2]; acc[ct][3] += p[3];
    }
  float xns = (l < 16) ? (xnL[0][l] + xnL[1][l] + xnL[2][l] + xnL[3][l]) : 0.f;

  // ---- epilogue, all in registers ----
  const float cnl = ws[8 + l];                     // cnorm[col l]
  const int tgl = (l < 16) ? tg[row0 + l] : 0;     // target of row l
  const unsigned long long pmv = *(const unsigned long long*)((const char*)ws + 16);
  float cn[4];
#pragma unroll
  for (int ct = 0; ct < 4; ++ct) cn[ct] = __shfl(cnl, ct * 16 + rlo);
  // col validity independent of row: col < NC && present
  bool cv[4];
#pragma unroll
  for (int ct = 0; ct < 4; ++ct) {
    const int col = ct * 16 + rlo;
    cv[ct] = (col < NC) && (((pmv >> col) & 1ull) != 0ull);
  }

  const int g4 = (l >> 4) * 4;  // first row of this lane's row-group
  float wl = 0.f, wp = 0.f;
#pragma unroll
  for (int r = 0; r < 4; ++r) {
    const int row = g4 + r;
    const int tjr = __shfl(tgl, row);
    const float xnr = __shfl(xns, row);
    const float s0 = fmaxf(xnr + cn[0] - 2.0f * acc[0][r], 1e-12f);
    const float s1 = fmaxf(xnr + cn[1] - 2.0f * acc[1][r], 1e-12f);
    const float s2 = fmaxf(xnr + cn[2] - 2.0f * acc[2][r], 1e-12f);
    const float s3 = fmaxf(xnr + cn[3] - 2.0f * acc[3][r], 1e-12f);
    // hardest positive: D[row, tjr]
    const int c2 = tjr >> 4;
    const float dsel = (c2 == 0) ? s0 : (c2 == 1) ? s1 : (c2 == 2) ? s2 : s3;
    const float apq = __shfl(dsel, (l & 48) | (tjr & 15));
    // hardest negative: min over valid cols != tjr
    const float INF = __builtin_inff();
    float m0 = (cv[0] && (rlo != tjr)) ? s0 : INF;
    float m1 = (cv[1] && (16 + rlo != tjr)) ? s1 : INF;
    float m2 = (cv[2] && (32 + rlo != tjr)) ? s2 : INF;
    float m3 = (cv[3] && (48 + rlo != tjr)) ? s3 : INF;
    float mn = fminf(fminf(m0, m1), fminf(m2, m3));
    mn = fminf(mn, __shfl_xor(mn, 1));
    mn = fminf(mn, __shfl_xor(mn, 2));
    mn = fminf(mn, __shfl_xor(mn, 4));
    mn = fminf(mn, __shfl_xor(mn, 8));
    if (rlo == 0) {
      const float ap = sqrtf(apq), an = sqrtf(mn);
      wl += fmaxf(ap - an + TCL_MARGIN, 0.f);
      wp += (an > ap) ? 1.f : 0.f;
    }
  }
  wl += __shfl_xor(wl, 16); wl += __shfl_xor(wl, 32);
  wp += __shfl_xor(wp, 16); wp += __shfl_xor(wp, 32);

  if (l == 0) {
    atomicAdd(&ws[0], wl);
    atomicAdd(&ws[1], wp);
    __threadfence();
    const unsigned int prev = atomicAdd((unsigned int*)ws + 2, 1u);
    if (prev == (unsigned int)(nblocks - 1)) {
      __threadfence();
      out[0] = atomicAdd(&ws[0], 0.f) * (1.0f / NB);
      out[1] = atomicAdd(&ws[1], 0.f) * (1.0f / NB);
    }
  }
}

extern "C" void kernel_launch(void* const* d_in, const int* in_sizes, int n_in,
                              void* d_out, int out_size, void* d_ws, size_t ws_size,
                              hipStream_t stream) {
  const float* x = (const float*)d_in[0];    // [8192, 512] f32
  const int* tg = (const int*)d_in[1];       // [8192] int32
  const float* cen = (const float*)d_in[2];  // [55, 512] f32
  float* out = (float*)d_out;                // [loss, prec]
  float* ws = (float*)d_ws;

  tcl_prep<<<dim3(65), dim3(64), 0, stream>>>(cen, tg, ws);
  tcl_main<<<dim3(NB / 16), dim3(256), 0, stream>>>(x, tg, ws, out, NB / 16);
}

// Round 6
// 23.535 us; speedup vs baseline: 2.2678x; 1.7763x over previous
//
#include <hip/hip_runtime.h>
#include <math.h>

#define NB 8192
#define ND 512
#define NC 55
#define TCL_MARGIN 0.2f

typedef __attribute__((ext_vector_type(8))) short short8;
typedef __attribute__((ext_vector_type(4))) short shortx4;
typedef __attribute__((ext_vector_type(4))) float f32x4;

// round-to-nearest-even fp32 -> bf16 (bit trick, sign-safe)
__device__ __forceinline__ unsigned short bf16rne(float v) {
  unsigned int u = __float_as_uint(v);
  unsigned int r = u + 0x7FFFu + ((u >> 16) & 1u);
  return (unsigned short)(r >> 16);
}

// split one f32 into bf16 hi (bits 31:16 of result) + bf16 lo residual (15:0)
__device__ __forceinline__ unsigned int bfsplit2(float v) {
  unsigned short hu = bf16rne(v);
  unsigned short lu = bf16rne(v - __uint_as_float((unsigned)hu << 16));
  return ((unsigned int)hu << 16) | (unsigned int)lu;
}

// ws layout (bytes):
//   16: presence u64
//   32..288:  cnorm[64] f32              (float idx 8..71)
//   512:      cenh bf16[64][512] (65536 B)
//   66048:    cenl bf16[64][512] (65536 B)
//   131584:   per-block partials float2[512] (4 KB) -- overwritten every call
#define PART_OFF 131584

__global__ __launch_bounds__(64)
void tcl_prep(const float* __restrict__ cen, const int* __restrict__ tg,
              float* __restrict__ ws) {
  const int c = blockIdx.x;   // 0..63 centers, 64 = presence bitmask
  const int t = threadIdx.x;  // 0..63

  if (c == 64) {
    // presence bitmask over all 8192 targets
    const int4* tg4 = (const int4*)tg;
    unsigned long long p0 = 0, p1 = 0, p2 = 0, p3 = 0;
    for (int g = 0; g < NB / 4; g += 256) {
      int4 a = tg4[g + t];
      int4 b = tg4[g + 64 + t];
      int4 e = tg4[g + 128 + t];
      int4 d = tg4[g + 192 + t];
      p0 |= (1ull << a.x) | (1ull << a.y) | (1ull << a.z) | (1ull << a.w);
      p1 |= (1ull << b.x) | (1ull << b.y) | (1ull << b.z) | (1ull << b.w);
      p2 |= (1ull << e.x) | (1ull << e.y) | (1ull << e.z) | (1ull << e.w);
      p3 |= (1ull << d.x) | (1ull << d.y) | (1ull << d.z) | (1ull << d.w);
    }
    unsigned long long pm = (p0 | p1) | (p2 | p3);
#pragma unroll
    for (int off = 32; off; off >>= 1) pm |= __shfl_xor(pm, off);
    if (t == 0) *(unsigned long long*)((char*)ws + 16) = pm;
    return;
  }

  // convert center row c -> bf16 hi/lo, compute cnorm
  unsigned short* ch = (unsigned short*)((char*)ws + 512) + c * ND;
  unsigned short* cl = (unsigned short*)((char*)ws + 66048) + c * ND;
  float s = 0.f;
#pragma unroll
  for (int i = 0; i < 2; ++i) {
    const int q = t + 64 * i;  // float4 index within the row
    float4 v = make_float4(0.f, 0.f, 0.f, 0.f);
    if (c < NC) v = ((const float4*)(cen + c * ND))[q];
    shortx4 h, lo;
    unsigned int p;
    p = bfsplit2(v.x); h.x = (short)(p >> 16); lo.x = (short)(p & 0xFFFF);
    p = bfsplit2(v.y); h.y = (short)(p >> 16); lo.y = (short)(p & 0xFFFF);
    p = bfsplit2(v.z); h.z = (short)(p >> 16); lo.z = (short)(p & 0xFFFF);
    p = bfsplit2(v.w); h.w = (short)(p >> 16); lo.w = (short)(p & 0xFFFF);
    s = fmaf(v.x, v.x, s); s = fmaf(v.y, v.y, s);
    s = fmaf(v.z, v.z, s); s = fmaf(v.w, v.w, s);
    *(shortx4*)(ch + q * 4) = h;
    *(shortx4*)(cl + q * 4) = lo;
  }
#pragma unroll
  for (int off = 32; off; off >>= 1) s += __shfl_xor(s, off);
  if (t == 0) ws[8 + c] = s;  // cnorm[c]
}

// Main: 512 blocks x 256 threads (4 waves). Block = 16 rows x 64 cols, K=512.
// Split-K: wave w handles K in [w*128, w*128+128). No global atomics: each
// block stores its (loss, prec) partial to its own float2 slot in ws.
__global__ __launch_bounds__(256)
void tcl_main(const float* __restrict__ x, const int* __restrict__ tg,
              float* __restrict__ ws) {
  __shared__ f32x4 accL[3][4][64];  // waves 1..3 partial accs, 12 KB
  __shared__ float xnL[4][16];      // per-wave partial row norms

  const int t = threadIdx.x;
  const int l = t & 63;
  const int w = t >> 6;
  const int row0 = blockIdx.x * 16;
  const int rlo = l & 15;        // A row within tile / B col within ct
  const int kgE = (l >> 4) * 8;  // element offset of this lane's k-group

  // ---- issue all 8 A loads (independent, in flight together) ----
  const float* xr = x + (row0 + rlo) * ND;
  float4 va[4][2];
#pragma unroll
  for (int ksl = 0; ksl < 4; ++ksl) {
    const int k0 = (w * 4 + ksl) * 32 + kgE;
    va[ksl][0] = *(const float4*)(xr + k0);
    va[ksl][1] = *(const float4*)(xr + k0 + 4);
  }

  // ---- row-norm partial over this wave's K range ----
  float xn = 0.f;
#pragma unroll
  for (int ksl = 0; ksl < 4; ++ksl) {
    float4 a = va[ksl][0], b = va[ksl][1];
    xn = fmaf(a.x, a.x, xn); xn = fmaf(a.y, a.y, xn);
    xn = fmaf(a.z, a.z, xn); xn = fmaf(a.w, a.w, xn);
    xn = fmaf(b.x, b.x, xn); xn = fmaf(b.y, b.y, xn);
    xn = fmaf(b.z, b.z, xn); xn = fmaf(b.w, b.w, xn);
  }
  xn += __shfl_xor(xn, 16);
  xn += __shfl_xor(xn, 32);
  if (l < 16) xnL[w][l] = xn;

  // ---- convert + MFMA: 4 k-steps x 4 col-tiles x 3 split-MFMAs ----
  f32x4 acc[4] = {{0.f,0.f,0.f,0.f},{0.f,0.f,0.f,0.f},{0.f,0.f,0.f,0.f},{0.f,0.f,0.f,0.f}};
  {
    const char* bh0 = (const char*)ws + 512 + rlo * 1024 + (l >> 4) * 16;
    const char* bl0 = (const char*)ws + 66048 + rlo * 1024 + (l >> 4) * 16;
#pragma unroll
    for (int ksl = 0; ksl < 4; ++ksl) {
      short8 ah, al;
      {
        float4 a = va[ksl][0], b = va[ksl][1];
        unsigned int p;
        p = bfsplit2(a.x); ah[0] = (short)(p >> 16); al[0] = (short)(p & 0xFFFF);
        p = bfsplit2(a.y); ah[1] = (short)(p >> 16); al[1] = (short)(p & 0xFFFF);
        p = bfsplit2(a.z); ah[2] = (short)(p >> 16); al[2] = (short)(p & 0xFFFF);
        p = bfsplit2(a.w); ah[3] = (short)(p >> 16); al[3] = (short)(p & 0xFFFF);
        p = bfsplit2(b.x); ah[4] = (short)(p >> 16); al[4] = (short)(p & 0xFFFF);
        p = bfsplit2(b.y); ah[5] = (short)(p >> 16); al[5] = (short)(p & 0xFFFF);
        p = bfsplit2(b.z); ah[6] = (short)(p >> 16); al[6] = (short)(p & 0xFFFF);
        p = bfsplit2(b.w); ah[7] = (short)(p >> 16); al[7] = (short)(p & 0xFFFF);
      }
      const int kb = (w * 4 + ksl) * 64;  // byte offset per k-chunk (32 elts * 2 B)
#pragma unroll
      for (int ct = 0; ct < 4; ++ct) {
        short8 bh = *(const short8*)(bh0 + ct * 16384 + kb);
        short8 bl = *(const short8*)(bl0 + ct * 16384 + kb);
        acc[ct] = __builtin_amdgcn_mfma_f32_16x16x32_bf16(ah, bh, acc[ct], 0, 0, 0);
        acc[ct] = __builtin_amdgcn_mfma_f32_16x16x32_bf16(al, bh, acc[ct], 0, 0, 0);
        acc[ct] = __builtin_amdgcn_mfma_f32_16x16x32_bf16(ah, bl, acc[ct], 0, 0, 0);
      }
    }
  }

  if (w) {
#pragma unroll
    for (int ct = 0; ct < 4; ++ct) accL[w - 1][ct][l] = acc[ct];
  }
  __syncthreads();
  if (w != 0) return;

  // ---- wave 0: reduce partials ----
#pragma unroll
  for (int wv = 0; wv < 3; ++wv)
#pragma unroll
    for (int ct = 0; ct < 4; ++ct) {
      f32x4 p = accL[wv][ct][l];
      acc[ct][0] += p[0]; acc[ct][1] += p[1];
      acc[ct][2] += p[2]; acc[ct][3] += p[3];
    }
  float xns = (l < 16) ? (xnL[0][l] + xnL[1][l] + xnL[2][l] + xnL[3][l]) : 0.f;

  // ---- epilogue, all in registers ----
  const float cnl = ws[8 + l];                     // cnorm[col l]
  const int tgl = (l < 16) ? tg[row0 + l] : 0;     // target of row l
  const unsigned long long pmv = *(const unsigned long long*)((const char*)ws + 16);
  float cn[4];
#pragma unroll
  for (int ct = 0; ct < 4; ++ct) cn[ct] = __shfl(cnl, ct * 16 + rlo);
  // col validity independent of row: col < NC && present
  bool cv[4];
#pragma unroll
  for (int ct = 0; ct < 4; ++ct) {
    const int col = ct * 16 + rlo;
    cv[ct] = (col < NC) && (((pmv >> col) & 1ull) != 0ull);
  }

  const int g4 = (l >> 4) * 4;  // first row of this lane's row-group
  float wl = 0.f, wp = 0.f;
#pragma unroll
  for (int r = 0; r < 4; ++r) {
    const int row = g4 + r;
    const int tjr = __shfl(tgl, row);
    const float xnr = __shfl(xns, row);
    const float s0 = fmaxf(xnr + cn[0] - 2.0f * acc[0][r], 1e-12f);
    const float s1 = fmaxf(xnr + cn[1] - 2.0f * acc[1][r], 1e-12f);
    const float s2 = fmaxf(xnr + cn[2] - 2.0f * acc[2][r], 1e-12f);
    const float s3 = fmaxf(xnr + cn[3] - 2.0f * acc[3][r], 1e-12f);
    // hardest positive: D[row, tjr]
    const int c2 = tjr >> 4;
    const float dsel = (c2 == 0) ? s0 : (c2 == 1) ? s1 : (c2 == 2) ? s2 : s3;
    const float apq = __shfl(dsel, (l & 48) | (tjr & 15));
    // hardest negative: min over valid cols != tjr
    const float INF = __builtin_inff();
    float m0 = (cv[0] && (rlo != tjr)) ? s0 : INF;
    float m1 = (cv[1] && (16 + rlo != tjr)) ? s1 : INF;
    float m2 = (cv[2] && (32 + rlo != tjr)) ? s2 : INF;
    float m3 = (cv[3] && (48 + rlo != tjr)) ? s3 : INF;
    float mn = fminf(fminf(m0, m1), fminf(m2, m3));
    mn = fminf(mn, __shfl_xor(mn, 1));
    mn = fminf(mn, __shfl_xor(mn, 2));
    mn = fminf(mn, __shfl_xor(mn, 4));
    mn = fminf(mn, __shfl_xor(mn, 8));
    if (rlo == 0) {
      const float ap = sqrtf(apq), an = sqrtf(mn);
      wl += fmaxf(ap - an + TCL_MARGIN, 0.f);
      wp += (an > ap) ? 1.f : 0.f;
    }
  }
  wl += __shfl_xor(wl, 16); wl += __shfl_xor(wl, 32);
  wp += __shfl_xor(wp, 16); wp += __shfl_xor(wp, 32);

  // ---- per-block partial slot (no atomics, overwritten every call) ----
  if (l == 0) {
    ((float2*)((char*)ws + PART_OFF))[blockIdx.x] = make_float2(wl, wp);
  }
}

// Finalize: 1 block x 256 threads reduces 512 float2 partials -> out[0..1]
__global__ __launch_bounds__(256)
void tcl_fin(const float* __restrict__ ws, float* __restrict__ out) {
  __shared__ float2 wsum[4];
  const int t = threadIdx.x;
  const float2* p = (const float2*)((const char*)ws + PART_OFF);
  float L = p[t].x + p[t + 256].x;
  float P = p[t].y + p[t + 256].y;
#pragma unroll
  for (int off = 32; off; off >>= 1) {
    L += __shfl_xor(L, off);
    P += __shfl_xor(P, off);
  }
  if ((t & 63) == 0) wsum[t >> 6] = make_float2(L, P);
  __syncthreads();
  if (t == 0) {
    const float l = wsum[0].x + wsum[1].x + wsum[2].x + wsum[3].x;
    const float pr = wsum[0].y + wsum[1].y + wsum[2].y + wsum[3].y;
    out[0] = l * (1.0f / NB);
    out[1] = pr * (1.0f / NB);
  }
}

extern "C" void kernel_launch(void* const* d_in, const int* in_sizes, int n_in,
                              void* d_out, int out_size, void* d_ws, size_t ws_size,
                              hipStream_t stream) {
  const float* x = (const float*)d_in[0];    // [8192, 512] f32
  const int* tg = (const int*)d_in[1];       // [8192] int32
  const float* cen = (const float*)d_in[2];  // [55, 512] f32
  float* out = (float*)d_out;                // [loss, prec]
  float* ws = (float*)d_ws;

  tcl_prep<<<dim3(65), dim3(64), 0, stream>>>(cen, tg, ws);
  tcl_main<<<dim3(NB / 16), dim3(256), 0, stream>>>(x, tg, ws);
  tcl_fin<<<dim3(1), dim3(256), 0, stream>>>(ws, out);
}

// Round 7
// 18.964 us; speedup vs baseline: 2.8143x; 1.2410x over previous
//
#include <hip/hip_runtime.h>
#include <math.h>

#define NB 8192
#define ND 512
#define NC 55
#define TCL_MARGIN 0.2f

typedef __attribute__((ext_vector_type(8))) short short8;
typedef __attribute__((ext_vector_type(4))) float f32x4;

// round-to-nearest-even fp32 -> bf16 (bit trick, sign-safe)
__device__ __forceinline__ unsigned short bf16rne(float v) {
  unsigned int u = __float_as_uint(v);
  unsigned int r = u + 0x7FFFu + ((u >> 16) & 1u);
  return (unsigned short)(r >> 16);
}

// split one f32 into bf16 hi (bits 31:16 of result) + bf16 lo residual (15:0)
__device__ __forceinline__ unsigned int bfsplit2(float v) {
  unsigned short hu = bf16rne(v);
  unsigned short lu = bf16rne(v - __uint_as_float((unsigned)hu << 16));
  return ((unsigned int)hu << 16) | (unsigned int)lu;
}

// ws layout: float2 partials[512] at offset 0 (4 KB), fully rewritten each call.

// Main: 512 blocks x 256 threads (4 waves). Block = 16 rows x 64 cols, K=512.
// Split-K: wave w handles K in [w*128, w*128+128). Fully self-contained:
// A and B both loaded as fp32 and converted to bf16 hi/lo in registers
// (B from L2-resident centers; identical arithmetic to the old prep path).
// cnorm/xnorm/presence computed in-kernel. No global atomics.
__global__ __launch_bounds__(256)
void tcl_main(const float* __restrict__ x, const int* __restrict__ tg,
              const float* __restrict__ cen, float* __restrict__ ws) {
  __shared__ f32x4 accL[3][4][64];   // waves 1..3 partial accs, 12 KB
  __shared__ float xnL[4][16];       // per-wave partial row norms
  __shared__ float cnL[4][4][16];    // per-wave partial col norms [w][ct][rlo]
  __shared__ unsigned long long pmL[4];

  const int t = threadIdx.x;
  const int l = t & 63;
  const int w = t >> 6;
  const int row0 = blockIdx.x * 16;
  const int rlo = l & 15;        // A row within tile / B col within ct
  const int kgE = (l >> 4) * 8;  // element offset of this lane's k-group

  // ---- issue all 8 A loads (independent, in flight together) ----
  const float* xr = x + (row0 + rlo) * ND;
  float4 va[4][2];
#pragma unroll
  for (int ksl = 0; ksl < 4; ++ksl) {
    const int k0 = (w * 4 + ksl) * 32 + kgE;
    va[ksl][0] = *(const float4*)(xr + k0);
    va[ksl][1] = *(const float4*)(xr + k0 + 4);
  }

  // ---- presence bitmask: 8 int4 loads/thread, all in flight (L2-resident) ----
  unsigned long long pm = 0ull;
  {
    const int4* tg4 = (const int4*)tg;
#pragma unroll
    for (int g = 0; g < 8; ++g) {
      int4 v = tg4[t + g * 256];
      pm |= (1ull << v.x) | (1ull << v.y) | (1ull << v.z) | (1ull << v.w);
    }
#pragma unroll
    for (int off = 32; off; off >>= 1) pm |= __shfl_xor(pm, off);
    if (l == 0) pmL[w] = pm;
  }

  // ---- row-norm partial over this wave's K range ----
  float xn = 0.f;
#pragma unroll
  for (int ksl = 0; ksl < 4; ++ksl) {
    float4 a = va[ksl][0], b = va[ksl][1];
    xn = fmaf(a.x, a.x, xn); xn = fmaf(a.y, a.y, xn);
    xn = fmaf(a.z, a.z, xn); xn = fmaf(a.w, a.w, xn);
    xn = fmaf(b.x, b.x, xn); xn = fmaf(b.y, b.y, xn);
    xn = fmaf(b.z, b.z, xn); xn = fmaf(b.w, b.w, xn);
  }
  xn += __shfl_xor(xn, 16);
  xn += __shfl_xor(xn, 32);
  if (l < 16) xnL[w][l] = xn;

  // ---- B column bases (cols >= 55 clamp to 54; masked in epilogue) ----
  const float* cb[4];
#pragma unroll
  for (int ct = 0; ct < 4; ++ct) {
    int col = ct * 16 + rlo;
    if (col > NC - 1) col = NC - 1;
    cb[ct] = cen + col * ND + kgE;
  }

  // ---- convert + MFMA: 4 k-steps x 4 col-tiles x 3 split-MFMAs ----
  f32x4 acc[4] = {{0.f,0.f,0.f,0.f},{0.f,0.f,0.f,0.f},{0.f,0.f,0.f,0.f},{0.f,0.f,0.f,0.f}};
  float cnp[4] = {0.f, 0.f, 0.f, 0.f};
#pragma unroll
  for (int ksl = 0; ksl < 4; ++ksl) {
    short8 ah, al;
    {
      float4 a = va[ksl][0], b = va[ksl][1];
      unsigned int p;
      p = bfsplit2(a.x); ah[0] = (short)(p >> 16); al[0] = (short)(p & 0xFFFF);
      p = bfsplit2(a.y); ah[1] = (short)(p >> 16); al[1] = (short)(p & 0xFFFF);
      p = bfsplit2(a.z); ah[2] = (short)(p >> 16); al[2] = (short)(p & 0xFFFF);
      p = bfsplit2(a.w); ah[3] = (short)(p >> 16); al[3] = (short)(p & 0xFFFF);
      p = bfsplit2(b.x); ah[4] = (short)(p >> 16); al[4] = (short)(p & 0xFFFF);
      p = bfsplit2(b.y); ah[5] = (short)(p >> 16); al[5] = (short)(p & 0xFFFF);
      p = bfsplit2(b.z); ah[6] = (short)(p >> 16); al[6] = (short)(p & 0xFFFF);
      p = bfsplit2(b.w); ah[7] = (short)(p >> 16); al[7] = (short)(p & 0xFFFF);
    }
    const int ko = (w * 4 + ksl) * 32;
#pragma unroll
    for (int ct = 0; ct < 4; ++ct) {
      float4 b0 = *(const float4*)(cb[ct] + ko);
      float4 b1 = *(const float4*)(cb[ct] + ko + 4);
      float c = cnp[ct];
      c = fmaf(b0.x, b0.x, c); c = fmaf(b0.y, b0.y, c);
      c = fmaf(b0.z, b0.z, c); c = fmaf(b0.w, b0.w, c);
      c = fmaf(b1.x, b1.x, c); c = fmaf(b1.y, b1.y, c);
      c = fmaf(b1.z, b1.z, c); c = fmaf(b1.w, b1.w, c);
      cnp[ct] = c;
      short8 bh, bl;
      unsigned int p;
      p = bfsplit2(b0.x); bh[0] = (short)(p >> 16); bl[0] = (short)(p & 0xFFFF);
      p = bfsplit2(b0.y); bh[1] = (short)(p >> 16); bl[1] = (short)(p & 0xFFFF);
      p = bfsplit2(b0.z); bh[2] = (short)(p >> 16); bl[2] = (short)(p & 0xFFFF);
      p = bfsplit2(b0.w); bh[3] = (short)(p >> 16); bl[3] = (short)(p & 0xFFFF);
      p = bfsplit2(b1.x); bh[4] = (short)(p >> 16); bl[4] = (short)(p & 0xFFFF);
      p = bfsplit2(b1.y); bh[5] = (short)(p >> 16); bl[5] = (short)(p & 0xFFFF);
      p = bfsplit2(b1.z); bh[6] = (short)(p >> 16); bl[6] = (short)(p & 0xFFFF);
      p = bfsplit2(b1.w); bh[7] = (short)(p >> 16); bl[7] = (short)(p & 0xFFFF);
      acc[ct] = __builtin_amdgcn_mfma_f32_16x16x32_bf16(ah, bh, acc[ct], 0, 0, 0);
      acc[ct] = __builtin_amdgcn_mfma_f32_16x16x32_bf16(al, bh, acc[ct], 0, 0, 0);
      acc[ct] = __builtin_amdgcn_mfma_f32_16x16x32_bf16(ah, bl, acc[ct], 0, 0, 0);
    }
  }

  // ---- col-norm partials: reduce the 4 k-groups, store per wave ----
#pragma unroll
  for (int ct = 0; ct < 4; ++ct) {
    float c = cnp[ct];
    c += __shfl_xor(c, 16);
    c += __shfl_xor(c, 32);
    if (l < 16) cnL[w][ct][l] = c;
  }

  if (w) {
#pragma unroll
    for (int ct = 0; ct < 4; ++ct) accL[w - 1][ct][l] = acc[ct];
  }
  __syncthreads();
  if (w != 0) return;

  // ---- wave 0: reduce partials ----
#pragma unroll
  for (int wv = 0; wv < 3; ++wv)
#pragma unroll
    for (int ct = 0; ct < 4; ++ct) {
      f32x4 p = accL[wv][ct][l];
      acc[ct][0] += p[0]; acc[ct][1] += p[1];
      acc[ct][2] += p[2]; acc[ct][3] += p[3];
    }
  float xns = (l < 16) ? (xnL[0][l] + xnL[1][l] + xnL[2][l] + xnL[3][l]) : 0.f;
  const unsigned long long pmv = pmL[0] | pmL[1] | pmL[2] | pmL[3];

  float cn[4];
  bool cv[4];
#pragma unroll
  for (int ct = 0; ct < 4; ++ct) {
    cn[ct] = cnL[0][ct][rlo] + cnL[1][ct][rlo] + cnL[2][ct][rlo] + cnL[3][ct][rlo];
    const int col = ct * 16 + rlo;
    cv[ct] = (col < NC) && (((pmv >> col) & 1ull) != 0ull);
  }

  const int tgl = (l < 16) ? tg[row0 + l] : 0;  // target of row l
  const int g4 = (l >> 4) * 4;                  // first row of this lane's row-group
  float wl = 0.f, wp = 0.f;
#pragma unroll
  for (int r = 0; r < 4; ++r) {
    const int row = g4 + r;
    const int tjr = __shfl(tgl, row);
    const float xnr = __shfl(xns, row);
    const float s0 = fmaxf(xnr + cn[0] - 2.0f * acc[0][r], 1e-12f);
    const float s1 = fmaxf(xnr + cn[1] - 2.0f * acc[1][r], 1e-12f);
    const float s2 = fmaxf(xnr + cn[2] - 2.0f * acc[2][r], 1e-12f);
    const float s3 = fmaxf(xnr + cn[3] - 2.0f * acc[3][r], 1e-12f);
    // hardest positive: D[row, tjr]
    const int c2 = tjr >> 4;
    const float dsel = (c2 == 0) ? s0 : (c2 == 1) ? s1 : (c2 == 2) ? s2 : s3;
    const float apq = __shfl(dsel, (l & 48) | (tjr & 15));
    // hardest negative: min over valid cols != tjr
    const float INF = __builtin_inff();
    float m0 = (cv[0] && (rlo != tjr)) ? s0 : INF;
    float m1 = (cv[1] && (16 + rlo != tjr)) ? s1 : INF;
    float m2 = (cv[2] && (32 + rlo != tjr)) ? s2 : INF;
    float m3 = (cv[3] && (48 + rlo != tjr)) ? s3 : INF;
    float mn = fminf(fminf(m0, m1), fminf(m2, m3));
    mn = fminf(mn, __shfl_xor(mn, 1));
    mn = fminf(mn, __shfl_xor(mn, 2));
    mn = fminf(mn, __shfl_xor(mn, 4));
    mn = fminf(mn, __shfl_xor(mn, 8));
    if (rlo == 0) {
      const float ap = sqrtf(apq), an = sqrtf(mn);
      wl += fmaxf(ap - an + TCL_MARGIN, 0.f);
      wp += (an > ap) ? 1.f : 0.f;
    }
  }
  wl += __shfl_xor(wl, 16); wl += __shfl_xor(wl, 32);
  wp += __shfl_xor(wp, 16); wp += __shfl_xor(wp, 32);

  // ---- per-block partial slot (no atomics, overwritten every call) ----
  if (l == 0) {
    ((float2*)ws)[blockIdx.x] = make_float2(wl, wp);
  }
}

// Finalize: 1 block x 256 threads reduces 512 float2 partials -> out[0..1]
__global__ __launch_bounds__(256)
void tcl_fin(const float* __restrict__ ws, float* __restrict__ out) {
  __shared__ float2 wsum[4];
  const int t = threadIdx.x;
  const float2* p = (const float2*)ws;
  float L = p[t].x + p[t + 256].x;
  float P = p[t].y + p[t + 256].y;
#pragma unroll
  for (int off = 32; off; off >>= 1) {
    L += __shfl_xor(L, off);
    P += __shfl_xor(P, off);
  }
  if ((t & 63) == 0) wsum[t >> 6] = make_float2(L, P);
  __syncthreads();
  if (t == 0) {
    const float l = wsum[0].x + wsum[1].x + wsum[2].x + wsum[3].x;
    const float pr = wsum[0].y + wsum[1].y + wsum[2].y + wsum[3].y;
    out[0] = l * (1.0f / NB);
    out[1] = pr * (1.0f / NB);
  }
}

extern "C" void kernel_launch(void* const* d_in, const int* in_sizes, int n_in,
                              void* d_out, int out_size, void* d_ws, size_t ws_size,
                              hipStream_t stream) {
  const float* x = (const float*)d_in[0];    // [8192, 512] f32
  const int* tg = (const int*)d_in[1];       // [8192] int32
  const float* cen = (const float*)d_in[2];  // [55, 512] f32
  float* out = (float*)d_out;                // [loss, prec]
  float* ws = (float*)d_ws;

  tcl_main<<<dim3(NB / 16), dim3(256), 0, stream>>>(x, tg, cen, ws);
  tcl_fin<<<dim3(1), dim3(256), 0, stream>>>(ws, out);
}